// Round 1
// baseline (434.796 us; speedup 1.0000x reference)
//
#include <hip/hip_runtime.h>
#include <hip/hip_bf16.h>

// Problem: B=8192, D_IN=1024, D_OUT=1024, E=16
#define NB 8192
#define DIN 1024
#define DOUT 1024
#define NE 16

typedef __attribute__((ext_vector_type(8))) short bf16x8;
typedef __attribute__((ext_vector_type(4))) short short4_t;
typedef __attribute__((ext_vector_type(4))) float f32x4;

__device__ __forceinline__ unsigned short f32_to_bf16(float f) {
  unsigned int u = __float_as_uint(f);
  u += 0x7FFFu + ((u >> 16) & 1u);   // RNE
  return (unsigned short)(u >> 16);
}

__device__ __forceinline__ void gl_lds16(const void* gp, void* lp) {
  __builtin_amdgcn_global_load_lds(
      (const __attribute__((address_space(1))) void*)gp,
      (__attribute__((address_space(3))) void*)lp, 16, 0, 0);
}

// ---------------- Kernel 1: gate softmax (f32) + x -> bf16 cast --------------
// 4 waves/block, one row per wave. Lane l owns x[row, j*256 + l*4 + t].
__global__ __launch_bounds__(256) void gate_cast_kernel(
    const float* __restrict__ x, const float* __restrict__ Wg,
    const float* __restrict__ bg, float* __restrict__ gout,
    unsigned short* __restrict__ xbf) {
  const int lane = threadIdx.x & 63;
  const int wid = threadIdx.x >> 6;
  const int row = blockIdx.x * 4 + wid;

  const f32x4* xr = (const f32x4*)(x + (size_t)row * DIN);
  f32x4 xv[4];
#pragma unroll
  for (int j = 0; j < 4; ++j) xv[j] = xr[j * 64 + lane];

  float acc[NE];
#pragma unroll
  for (int e = 0; e < NE; ++e) acc[e] = 0.f;

#pragma unroll
  for (int j = 0; j < 4; ++j) {
#pragma unroll
    for (int t = 0; t < 4; ++t) {
      const int i = j * 256 + lane * 4 + t;
      const f32x4* wrow = (const f32x4*)(Wg + (size_t)i * NE);
      const f32x4 w0 = wrow[0], w1 = wrow[1], w2 = wrow[2], w3 = wrow[3];
      const float xx = xv[j][t];
#pragma unroll
      for (int q = 0; q < 4; ++q) {
        acc[q]      = fmaf(xx, w0[q], acc[q]);
        acc[4 + q]  = fmaf(xx, w1[q], acc[4 + q]);
        acc[8 + q]  = fmaf(xx, w2[q], acc[8 + q]);
        acc[12 + q] = fmaf(xx, w3[q], acc[12 + q]);
      }
    }
  }
  // butterfly reduce across 64 lanes
#pragma unroll
  for (int off = 32; off >= 1; off >>= 1) {
#pragma unroll
    for (int e = 0; e < NE; ++e) acc[e] += __shfl_xor(acc[e], off, 64);
  }
#pragma unroll
  for (int e = 0; e < NE; ++e) acc[e] += bg[e];
  float mx = acc[0];
#pragma unroll
  for (int e = 1; e < NE; ++e) mx = fmaxf(mx, acc[e]);
  float p[NE];
  float s = 0.f;
#pragma unroll
  for (int e = 0; e < NE; ++e) { p[e] = expf(acc[e] - mx); s += p[e]; }
  const float inv = 1.f / s;
  if (lane == 0) {
#pragma unroll
    for (int e = 0; e < NE; ++e) gout[(size_t)row * NE + e] = p[e] * inv;
  }
  // cast this row to bf16 (coalesced 8B stores)
#pragma unroll
  for (int j = 0; j < 4; ++j) {
    short4_t o;
#pragma unroll
    for (int t = 0; t < 4; ++t) o[t] = (short)f32_to_bf16(xv[j][t]);
    *(short4_t*)(xbf + (size_t)row * DIN + j * 256 + lane * 4) = o;
  }
}

// ------------- Kernel 2: We[e,i,o] f32 -> WeT[e,o,i] bf16 (transpose) --------
__global__ __launch_bounds__(256) void we_transpose_kernel(
    const float* __restrict__ We, unsigned short* __restrict__ WeT) {
  __shared__ float tile[64][65];
  const int e = blockIdx.z, it = blockIdx.y, ot = blockIdx.x;
  const int tr = threadIdx.x >> 4;        // 0..15
  const int tc = (threadIdx.x & 15) * 4;  // 0..60
  const float* src = We + (((size_t)e * DIN + it * 64) * DOUT) + ot * 64;
#pragma unroll
  for (int rr = 0; rr < 64; rr += 16) {
    const f32x4 v = *(const f32x4*)(src + (size_t)(rr + tr) * DOUT + tc);
#pragma unroll
    for (int t = 0; t < 4; ++t) tile[rr + tr][tc + t] = v[t];
  }
  __syncthreads();
  unsigned short* dst = WeT + (((size_t)e * DOUT + ot * 64) * DIN) + it * 64;
#pragma unroll
  for (int rr = 0; rr < 64; rr += 16) {
    short4_t o;
#pragma unroll
    for (int t = 0; t < 4; ++t) o[t] = (short)f32_to_bf16(tile[tc + t][rr + tr]);
    *(short4_t*)(dst + (size_t)(rr + tr) * DIN + tc) = o;
  }
}

// ------------- Kernel 3: fused MoE GEMM, K = 16*1024, gate-rescaled ----------
// 128x128 tile, BK=32, 4 waves, each wave 64x64 = 4x4 frags of 16x16x32 bf16.
#define BM 128
#define BN 128
#define BK 32

__global__ __launch_bounds__(256) void moe_gemm_kernel(
    const unsigned short* __restrict__ xbf,   // [8192][1024] bf16
    const unsigned short* __restrict__ WeT,   // [16][1024(o)][1024(i)] bf16
    const float* __restrict__ g,              // [8192][16]
    const float* __restrict__ be,             // [16][1024]
    float* __restrict__ out) {                // [8192][1024] f32
  __shared__ unsigned short As[BM * BK];      // 8KB, [row][k]
  __shared__ unsigned short Bs[BN * BK];      // 8KB, [col][k] (B^T)
  __shared__ float gs[BM][NE];                // 8KB

  const int tid = threadIdx.x;
  const int lane = tid & 63, wid = tid >> 6;
  const int wr = wid >> 1, wc = wid & 1;
  const int l15 = lane & 15, l4 = lane >> 4;

  // XCD swizzle: consecutive bids round-robin XCDs; give each XCD one B panel.
  const int bid = blockIdx.x;
  const int bcol = (bid & 7) * BN;
  const int brow = (bid >> 3) * BM;

  { // stage gate probs for this row-tile
    const f32x4* gsrc = (const f32x4*)(g + (size_t)brow * NE);
    f32x4* gdst = (f32x4*)&gs[0][0];
    gdst[tid] = gsrc[tid];
    gdst[tid + 256] = gsrc[tid + 256];
  }

  f32x4 acc[4][4];
#pragma unroll
  for (int m = 0; m < 4; ++m)
#pragma unroll
    for (int n = 0; n < 4; ++n) acc[m][n] = (f32x4){0.f, 0.f, 0.f, 0.f};

  const int srow = tid >> 2;          // staging: chunk row 0..63
  const int scol = (tid & 3) * 8;     // staging: k-offset within BK
  const unsigned short* aG = xbf + (size_t)(brow + srow) * DIN + scol;

  char* AsLds = (char*)As + wid * 1024;  // wave-uniform LDS dst base
  char* BsLds = (char*)Bs + wid * 1024;

  for (int e = 0; e < NE; ++e) {
    if (e > 0) {  // in-place gate rescale: acc *= g[r,e-1]/g[r,e]
#pragma unroll
      for (int m = 0; m < 4; ++m) {
        const int rb = wr * 64 + m * 16 + l4 * 4;
#pragma unroll
        for (int j = 0; j < 4; ++j) {
          const float r = gs[rb + j][e - 1] *
                          __builtin_amdgcn_rcpf(fmaxf(gs[rb + j][e], 1e-30f));
#pragma unroll
          for (int n = 0; n < 4; ++n) acc[m][n][j] *= r;
        }
      }
    }
    const unsigned short* bG =
        WeT + (size_t)e * (DOUT * DIN) + (size_t)(bcol + srow) * DIN + scol;
    for (int kt = 0; kt < DIN / BK; ++kt) {
      const int kk = kt * BK;
      __syncthreads();  // previous compute done -> safe to overwrite LDS
      gl_lds16(aG + kk, AsLds);
      gl_lds16(aG + 64 * DIN + kk, AsLds + 4096);
      gl_lds16(bG + kk, BsLds);
      gl_lds16(bG + 64 * DIN + kk, BsLds + 4096);
      __syncthreads();  // drains vmcnt(0): staged data visible
      bf16x8 af[4], bfr[4];
#pragma unroll
      for (int m = 0; m < 4; ++m)
        af[m] = *(const bf16x8*)(As + (wr * 64 + m * 16 + l15) * BK + l4 * 8);
#pragma unroll
      for (int n = 0; n < 4; ++n)
        bfr[n] = *(const bf16x8*)(Bs + (wc * 64 + n * 16 + l15) * BK + l4 * 8);
#pragma unroll
      for (int m = 0; m < 4; ++m)
#pragma unroll
        for (int n = 0; n < 4; ++n)
          acc[m][n] = __builtin_amdgcn_mfma_f32_16x16x32_bf16(
              af[m], bfr[n], acc[m][n], 0, 0, 0);
    }
    // bias: coefficient of a unit added now ends up exactly g[r,e]
#pragma unroll
    for (int n = 0; n < 4; ++n) {
      const float bv = be[e * DOUT + bcol + wc * 64 + n * 16 + l15];
#pragma unroll
      for (int m = 0; m < 4; ++m)
#pragma unroll
        for (int j = 0; j < 4; ++j) acc[m][n][j] += bv;
    }
  }
  // final scale by g[r, NE-1] and store
#pragma unroll
  for (int m = 0; m < 4; ++m) {
    const int rb = wr * 64 + m * 16 + l4 * 4;
#pragma unroll
    for (int j = 0; j < 4; ++j) {
      const float gf = gs[rb + j][NE - 1];
      const size_t orow = (size_t)brow + rb + j;
#pragma unroll
      for (int n = 0; n < 4; ++n)
        out[orow * DOUT + bcol + wc * 64 + n * 16 + l15] = acc[m][n][j] * gf;
    }
  }
}

// ---------------------------------------------------------------------------
extern "C" void kernel_launch(void* const* d_in, const int* in_sizes, int n_in,
                              void* d_out, int out_size, void* d_ws, size_t ws_size,
                              hipStream_t stream) {
  const float* x  = (const float*)d_in[0];   // [8192,1024]
  const float* Wg = (const float*)d_in[1];   // [1024,16]
  const float* bg = (const float*)d_in[2];   // [16]
  const float* We = (const float*)d_in[3];   // [16,1024,1024]
  const float* be = (const float*)d_in[4];   // [16,1024]
  float* out = (float*)d_out;                // [8192,1024]

  // workspace layout: x_bf16 (16 MiB) | WeT bf16 (32 MiB) | g (512 KiB)
  char* ws = (char*)d_ws;
  unsigned short* xbf = (unsigned short*)ws;
  unsigned short* WeT = (unsigned short*)(ws + (size_t)NB * DIN * 2);
  float* g = (float*)(ws + (size_t)NB * DIN * 2 + (size_t)NE * DIN * DOUT * 2);

  gate_cast_kernel<<<dim3(NB / 4), 256, 0, stream>>>(x, Wg, bg, g, xbf);
  we_transpose_kernel<<<dim3(DOUT / 64, DIN / 64, NE), 256, 0, stream>>>(We, WeT);
  moe_gemm_kernel<<<dim3((NB / BM) * (DOUT / BN)), 256, 0, stream>>>(
      xbf, WeT, g, be, out);
}